// Round 5
// baseline (173.948 us; speedup 1.0000x reference)
//
#include <hip/hip_runtime.h>

// Problem constants
#define B_   8
#define TE_  256
#define TD_  256
#define D_   256
#define U_   256

// Workspace layout (float offsets). ~6 MB.
#define EET_OFF   0        // (B, U, TE)  Ee^T = exp2(2log2e * en@w_en), TRANSPOSED
#define ED_OFF    524288   // (B, TD, U)  Ed = exp2(2log2e * de@w_de)
#define ALPHA_OFF 1048576  // (B, TD, TE) alphas
#define MAXMU_OFF 1572864  // (B, TD)     row max of mu'
#define HH_OFF    1574912  // (B, D)      h_hat

__device__ __forceinline__ float fexp2(float x) {
#if __has_builtin(__builtin_amdgcn_exp2f)
  return __builtin_amdgcn_exp2f(x);
#else
  return exp2f(x);
#endif
}
__device__ __forceinline__ float frcp(float x) {
#if __has_builtin(__builtin_amdgcn_rcpf)
  return __builtin_amdgcn_rcpf(x);
#else
  return 1.0f / x;
#endif
}

#define LOG2E_F 1.4426950408889634f
#define TWO_LOG2E_F 2.8853900817779268f

// ---------------------------------------------------------------------------
// K1 (zero-LDS GEMM, same pattern as K2/K4): block = 16 rows x 256 u-cols,
// thread = u. W[k][u]: lane-coalesced dword (L2-hot, 64 MB aggregate = 19 TB/s
// < L2 ceiling). A[row][k]: block-uniform -> s_load_dwordx4 (SGPR operands
// free in v_fma). 16 independent acc chains; NO barriers, NO LDS in main loop.
//   bi < 128: en -> EeT[b][u][t] (transposed; per-thread contiguous float4s)
//   bi >=128: de -> Ed[s][u]     (row-major; wave-coalesced dword stores)
// grid 256 blocks x 256 threads.
// ---------------------------------------------------------------------------
__global__ __launch_bounds__(256) void coatt_k1_proj(
    const float* __restrict__ en, const float* __restrict__ de,
    const float* __restrict__ w_en, const float* __restrict__ w_de,
    float* __restrict__ ws) {
  const int bi = blockIdx.x;
  const int which = bi >> 7;                 // 0: en, 1: de
  const float* __restrict__ A = which ? de : en;      // (2048, 256)
  const float* __restrict__ W = which ? w_de : w_en;  // (256, 256)
  const int rowBase = (bi & 127) * 16;
  const int u = threadIdx.x;

  float acc[16] = {};
#pragma unroll 4
  for (int k4 = 0; k4 < 64; ++k4) {
    float wv[4];
#pragma unroll
    for (int j = 0; j < 4; ++j) wv[j] = W[(k4 * 4 + j) * U_ + u];  // coalesced
#pragma unroll
    for (int i = 0; i < 16; ++i) {
      const float4 a4 = *(const float4*)&A[(rowBase + i) * D_ + k4 * 4];  // uniform -> SGPR
      acc[i] = fmaf(a4.x, wv[0], acc[i]);
      acc[i] = fmaf(a4.y, wv[1], acc[i]);
      acc[i] = fmaf(a4.z, wv[2], acc[i]);
      acc[i] = fmaf(a4.w, wv[3], acc[i]);
    }
  }

  if (which) {
    float* __restrict__ out = ws + ED_OFF;
#pragma unroll
    for (int i = 0; i < 16; ++i)
      out[(rowBase + i) * U_ + u] = fexp2(acc[i] * TWO_LOG2E_F);  // coalesced
  } else {
    float* __restrict__ out = ws + EET_OFF;
    const int b = rowBase >> 8, t0 = rowBase & 255;
    float* __restrict__ p = out + (size_t)(b * U_ + u) * TE_ + t0;
#pragma unroll
    for (int q = 0; q < 4; ++q) {
      float4 o;
      o.x = fexp2(acc[q * 4 + 0] * TWO_LOG2E_F);
      o.y = fexp2(acc[q * 4 + 1] * TWO_LOG2E_F);
      o.z = fexp2(acc[q * 4 + 2] * TWO_LOG2E_F);
      o.w = fexp2(acc[q * 4 + 3] * TWO_LOG2E_F);
      *(float4*)&p[q * 4] = o;  // per-thread contiguous
    }
  }
}

// ---------------------------------------------------------------------------
// K2 (dominant, trans-pipe-bound): per block (b, 4 s-rows), thread t = tid.
//   mu'[s][t] = -2 * sum_u nu_u * rcp(fma(Ed[s,u], EeT[u,t], 1))
// EeT read: coalesced global dword (lane=t). Ed/nu: wave-uniform -> s_load.
// ZERO LDS in the u-loop. Fused row-softmax over t.
// grid (64, 8) = 512 blocks.
// ---------------------------------------------------------------------------
__global__ __launch_bounds__(256) void coatt_k2_mu(
    const float* __restrict__ nu, float* __restrict__ ws) {
  const float* __restrict__ EeT = ws + EET_OFF;
  const float* __restrict__ Ed = ws + ED_OFF;
  float* __restrict__ alphas = ws + ALPHA_OFF;
  float* __restrict__ maxmu = ws + MAXMU_OFF;
  const int b = blockIdx.y;
  const int sBase = blockIdx.x * 4;
  const int tid = threadIdx.x;
  const int w = tid >> 6, lane = tid & 63;
  const float* __restrict__ Ee_b = EeT + (size_t)b * U_ * TE_ + tid;     // coalesced
  const float* __restrict__ Ed_b = Ed + (size_t)(b * TD_ + sBase) * U_;  // uniform

  float acc0 = 0.f, acc1 = 0.f, acc2 = 0.f, acc3 = 0.f;
#pragma unroll 4
  for (int u4 = 0; u4 < 64; ++u4) {
    const float4 nv = *(const float4*)&nu[u4 * 4];          // uniform -> SGPR
    const float4 e0 = *(const float4*)&Ed_b[0 * U_ + u4 * 4];
    const float4 e1 = *(const float4*)&Ed_b[1 * U_ + u4 * 4];
    const float4 e2 = *(const float4*)&Ed_b[2 * U_ + u4 * 4];
    const float4 e3 = *(const float4*)&Ed_b[3 * U_ + u4 * 4];
    float ee[4];
#pragma unroll
    for (int j = 0; j < 4; ++j) ee[j] = Ee_b[(u4 * 4 + j) * TE_];  // coalesced
    const float* nvp = (const float*)&nv;
    const float* p0 = (const float*)&e0;
    const float* p1 = (const float*)&e1;
    const float* p2 = (const float*)&e2;
    const float* p3 = (const float*)&e3;
#pragma unroll
    for (int j = 0; j < 4; ++j) {
      acc0 = fmaf(nvp[j], frcp(fmaf(p0[j], ee[j], 1.0f)), acc0);
      acc1 = fmaf(nvp[j], frcp(fmaf(p1[j], ee[j], 1.0f)), acc1);
      acc2 = fmaf(nvp[j], frcp(fmaf(p2[j], ee[j], 1.0f)), acc2);
      acc3 = fmaf(nvp[j], frcp(fmaf(p3[j], ee[j], 1.0f)), acc3);
    }
  }
  // mu' = -2*acc. Fused softmax over t (256 threads = 4 waves).
  float v[4] = {-2.f * acc0, -2.f * acc1, -2.f * acc2, -2.f * acc3};
  __shared__ float part[4][4];  // [s][wave]
  float m[4];
#pragma unroll
  for (int s = 0; s < 4; ++s) {
    m[s] = v[s];
#pragma unroll
    for (int off = 32; off > 0; off >>= 1) m[s] = fmaxf(m[s], __shfl_xor(m[s], off));
    if (lane == 0) part[s][w] = m[s];
  }
  __syncthreads();
#pragma unroll
  for (int s = 0; s < 4; ++s)
    m[s] = fmaxf(fmaxf(part[s][0], part[s][1]), fmaxf(part[s][2], part[s][3]));
  __syncthreads();
  float e[4], sm[4];
#pragma unroll
  for (int s = 0; s < 4; ++s) {
    e[s] = fexp2((v[s] - m[s]) * LOG2E_F);
    sm[s] = e[s];
#pragma unroll
    for (int off = 32; off > 0; off >>= 1) sm[s] += __shfl_xor(sm[s], off);
    if (lane == 0) part[s][w] = sm[s];
  }
  __syncthreads();
  float* __restrict__ al = alphas + (size_t)(b * TD_ + sBase) * TE_;
#pragma unroll
  for (int s = 0; s < 4; ++s) {
    const float tot = (part[s][0] + part[s][1]) + (part[s][2] + part[s][3]);
    al[s * TE_ + tid] = e[s] * frcp(tot);
  }
  if (tid == 0) {
#pragma unroll
    for (int s = 0; s < 4; ++s) maxmu[b * TD_ + sBase + s] = m[s];
  }
}

// ---------------------------------------------------------------------------
// K3: max_alphas = softmax_s(maxmu[b,:]); h_hat[b,d] = sum_s de[b,s,d]*ma[s].
// grid (8 dChunks, 8 b), 256 threads.
// ---------------------------------------------------------------------------
__global__ __launch_bounds__(256) void coatt_k3_hhat(
    const float* __restrict__ de, float* __restrict__ ws) {
  const float* __restrict__ maxmu = ws + MAXMU_OFF;
  float* __restrict__ hhat = ws + HH_OFF;
  const int b = blockIdx.y;
  const int dBase = blockIdx.x * 32;
  const int tid = threadIdx.x;
  const int w = tid >> 6, lane = tid & 63;
  __shared__ float red[8];
  __shared__ float malpha[256];
  __shared__ float acc_red[256];
  const float v = maxmu[b * TD_ + tid];
  float m = v;
#pragma unroll
  for (int off = 32; off > 0; off >>= 1) m = fmaxf(m, __shfl_xor(m, off));
  if (lane == 0) red[w] = m;
  __syncthreads();
  m = fmaxf(fmaxf(red[0], red[1]), fmaxf(red[2], red[3]));
  const float e = fexp2((v - m) * LOG2E_F);
  float sm = e;
#pragma unroll
  for (int off = 32; off > 0; off >>= 1) sm += __shfl_xor(sm, off);
  if (lane == 0) red[4 + w] = sm;
  __syncthreads();
  sm = (red[4] + red[5]) + (red[6] + red[7]);
  malpha[tid] = e * frcp(sm);
  __syncthreads();
  const int dl = tid & 31, sg = tid >> 5;
  float acc = 0.f;
  for (int s = sg * 32; s < sg * 32 + 32; ++s)
    acc = fmaf(de[(b * TD_ + s) * D_ + dBase + dl], malpha[s], acc);
  acc_red[tid] = acc;
  __syncthreads();
  if (tid < 32) {
    float t = acc_red[tid];
#pragma unroll
    for (int g = 1; g < 8; ++g) t += acc_red[g * 32 + tid];
    hhat[b * D_ + dBase + tid] = t;
  }
}

// ---------------------------------------------------------------------------
// K4: sum_en[s,d] = sum_t alphas[s,t]*en[t,d] with alphas via SCALAR loads
// (uniform per block) and en coalesced (lane=d). Fused concat epilogue:
// out = [de | sum_en | de*sum_en | de*h_hat]. grid (64, 8) = 512 blocks.
// ---------------------------------------------------------------------------
__global__ __launch_bounds__(256) void coatt_k4_out(
    const float* __restrict__ en, const float* __restrict__ de,
    const float* __restrict__ ws, float* __restrict__ out) {
  const float* __restrict__ alphas = ws + ALPHA_OFF;
  const float* __restrict__ hhat = ws + HH_OFF;
  const int b = blockIdx.y;
  const int sBase = blockIdx.x * 4;
  const int d = threadIdx.x;
  const float* __restrict__ al = alphas + (size_t)(b * TD_ + sBase) * TE_;  // uniform
  const float* __restrict__ en_b = en + (size_t)b * TE_ * D_ + d;           // coalesced

  float acc0 = 0.f, acc1 = 0.f, acc2 = 0.f, acc3 = 0.f;
#pragma unroll 4
  for (int t4 = 0; t4 < 64; ++t4) {
    const float4 a0 = *(const float4*)&al[0 * TE_ + t4 * 4];  // uniform -> SGPR
    const float4 a1 = *(const float4*)&al[1 * TE_ + t4 * 4];
    const float4 a2 = *(const float4*)&al[2 * TE_ + t4 * 4];
    const float4 a3 = *(const float4*)&al[3 * TE_ + t4 * 4];
    float env[4];
#pragma unroll
    for (int j = 0; j < 4; ++j) env[j] = en_b[(t4 * 4 + j) * D_];  // coalesced
    const float* q0 = (const float*)&a0;
    const float* q1 = (const float*)&a1;
    const float* q2 = (const float*)&a2;
    const float* q3 = (const float*)&a3;
#pragma unroll
    for (int j = 0; j < 4; ++j) {
      acc0 = fmaf(q0[j], env[j], acc0);
      acc1 = fmaf(q1[j], env[j], acc1);
      acc2 = fmaf(q2[j], env[j], acc2);
      acc3 = fmaf(q3[j], env[j], acc3);
    }
  }
  const float hh = hhat[b * D_ + d];
  const float se[4] = {acc0, acc1, acc2, acc3};
#pragma unroll
  for (int s = 0; s < 4; ++s) {
    const float dd = de[(size_t)(b * TD_ + sBase + s) * D_ + d];
    float* o = out + (size_t)(b * TD_ + sBase + s) * (4 * D_);
    o[d] = dd;
    o[D_ + d] = se[s];
    o[2 * D_ + d] = dd * se[s];
    o[3 * D_ + d] = dd * hh;
  }
}

extern "C" void kernel_launch(void* const* d_in, const int* in_sizes, int n_in,
                              void* d_out, int out_size, void* d_ws, size_t ws_size,
                              hipStream_t stream) {
  (void)in_sizes; (void)n_in; (void)out_size; (void)ws_size;
  const float* en   = (const float*)d_in[0];
  const float* de   = (const float*)d_in[1];
  const float* w_en = (const float*)d_in[2];
  const float* w_de = (const float*)d_in[3];
  const float* nu   = (const float*)d_in[4];
  float* out = (float*)d_out;
  float* ws  = (float*)d_ws;

  coatt_k1_proj<<<dim3(256), 256, 0, stream>>>(en, de, w_en, w_de, ws);
  coatt_k2_mu<<<dim3(64, 8), 256, 0, stream>>>(nu, ws);
  coatt_k3_hhat<<<dim3(8, 8), 256, 0, stream>>>(de, ws);
  coatt_k4_out<<<dim3(64, 8), 256, 0, stream>>>(en, de, ws, out);
}

// Round 6
// 138.736 us; speedup vs baseline: 1.2538x; 1.2538x over previous
//
#include <hip/hip_runtime.h>

// Problem constants
#define B_   8
#define TE_  256
#define TD_  256
#define D_   256
#define U_   256

// Workspace layout (float offsets). ~6 MB.
#define EET_OFF   0        // (B, U, TE)  Ee^T = exp2(2log2e * en@w_en), TRANSPOSED
#define ED_OFF    524288   // (B, TD, U)  Ed = exp2(2log2e * de@w_de)
#define ALPHA_OFF 1048576  // (B, TD, TE) alphas
#define MAXMU_OFF 1572864  // (B, TD)     row max of mu'
#define HH_OFF    1574912  // (B, D)      h_hat

__device__ __forceinline__ float fexp2(float x) {
#if __has_builtin(__builtin_amdgcn_exp2f)
  return __builtin_amdgcn_exp2f(x);
#else
  return exp2f(x);
#endif
}
__device__ __forceinline__ float frcp(float x) {
#if __has_builtin(__builtin_amdgcn_rcpf)
  return __builtin_amdgcn_rcpf(x);
#else
  return 1.0f / x;
#endif
}
// Broadcast a uniform value held in lane `l` of a wave-cooperatively loaded
// VGPR to all lanes via v_readlane (VALU; no LDS pipe, no SMEM latency).
__device__ __forceinline__ float rdlane(float v, int l) {
  return __int_as_float(__builtin_amdgcn_readlane(__float_as_int(v), l));
}

#define LOG2E_F 1.4426950408889634f
#define TWO_LOG2E_F 2.8853900817779268f

// ---------------------------------------------------------------------------
// K1 (readlane GEMM): block = 8 rows (4 waves x 2 rows) x 256 u; thread owns
// 2 rows x 4 u. Per 32-k chunk: ONE cooperative vector load grabs the wave's
// 2x32 A-tile (lane = row*32+k); v_readlane broadcasts each A value at use
// (rl:fma = 1:4). W loads are fully-coalesced b128. No SMEM scalar loads,
// no LDS in main loop. grid 512 (2 blocks/CU): bi<256 -> en->EeT (transposed
// via LDS epilogue), bi>=256 -> de->Ed (direct coalesced b128 stores).
// ---------------------------------------------------------------------------
__global__ __launch_bounds__(256) void coatt_k1_proj(
    const float* __restrict__ en, const float* __restrict__ de,
    const float* __restrict__ w_en, const float* __restrict__ w_de,
    float* __restrict__ ws) {
  const int bi = blockIdx.x;
  const int which = bi >> 8;                 // 0: en, 1: de
  const float* __restrict__ A = which ? de : en;      // (2048, 256)
  const float* __restrict__ W = which ? w_de : w_en;  // (256, 256)
  const int r0 = (bi & 255) * 8;             // block's global row base
  const int tid = threadIdx.x;
  const int w = tid >> 6, lane = tid & 63;
  const int rowW = r0 + w * 2;               // this wave's 2 rows
  const int u4 = lane * 4;

  // cooperative A pointer: lane -> (row = lane>>5, k = lane&31)
  const float* __restrict__ Arow = A + (size_t)(rowW + (lane >> 5)) * D_ + (lane & 31);

  float4 acc0 = {0, 0, 0, 0}, acc1 = {0, 0, 0, 0};
  for (int k0 = 0; k0 < D_; k0 += 32) {
    const float areg = Arow[k0];             // one vload: 2 rows x 32 k
#pragma unroll
    for (int h = 0; h < 2; ++h) {
      float4 wv[16];
#pragma unroll
      for (int k = 0; k < 16; ++k)
        wv[k] = *(const float4*)&W[(k0 + h * 16 + k) * U_ + u4];  // coalesced b128
#pragma unroll
      for (int k = 0; k < 16; ++k) {
        const float a0 = rdlane(areg, h * 16 + k);        // row 0
        const float a1 = rdlane(areg, 32 + h * 16 + k);   // row 1
        acc0.x = fmaf(a0, wv[k].x, acc0.x);
        acc0.y = fmaf(a0, wv[k].y, acc0.y);
        acc0.z = fmaf(a0, wv[k].z, acc0.z);
        acc0.w = fmaf(a0, wv[k].w, acc0.w);
        acc1.x = fmaf(a1, wv[k].x, acc1.x);
        acc1.y = fmaf(a1, wv[k].y, acc1.y);
        acc1.z = fmaf(a1, wv[k].z, acc1.z);
        acc1.w = fmaf(a1, wv[k].w, acc1.w);
      }
    }
  }

  __shared__ float TT[8][257];  // en-half transpose staging (8 t-rows x 256 u)
  if (which) {
    // Ed: rows ARE (b*TD+s); coalesced b128 stores
    float* __restrict__ out = ws + ED_OFF;
    float4 o0, o1;
    o0.x = fexp2(acc0.x * TWO_LOG2E_F); o0.y = fexp2(acc0.y * TWO_LOG2E_F);
    o0.z = fexp2(acc0.z * TWO_LOG2E_F); o0.w = fexp2(acc0.w * TWO_LOG2E_F);
    o1.x = fexp2(acc1.x * TWO_LOG2E_F); o1.y = fexp2(acc1.y * TWO_LOG2E_F);
    o1.z = fexp2(acc1.z * TWO_LOG2E_F); o1.w = fexp2(acc1.w * TWO_LOG2E_F);
    *(float4*)&out[(rowW + 0) * U_ + u4] = o0;
    *(float4*)&out[(rowW + 1) * U_ + u4] = o1;
  } else {
    // EeT[b][u][t]: transpose via LDS, then per-thread contiguous float4 x2
    const float* a0p = (const float*)&acc0;
    const float* a1p = (const float*)&acc1;
#pragma unroll
    for (int j = 0; j < 4; ++j) {
      TT[w * 2 + 0][u4 + j] = fexp2(a0p[j] * TWO_LOG2E_F);
      TT[w * 2 + 1][u4 + j] = fexp2(a1p[j] * TWO_LOG2E_F);
    }
    __syncthreads();
    const int b = r0 >> 8, t0 = r0 & 255;
    float v[8];
#pragma unroll
    for (int k = 0; k < 8; ++k) v[k] = TT[k][tid];  // conflict-free (stride 257)
    float* __restrict__ p = ws + EET_OFF + (size_t)(b * U_ + tid) * TE_ + t0;
    float4 q0, q1;
    q0.x = v[0]; q0.y = v[1]; q0.z = v[2]; q0.w = v[3];
    q1.x = v[4]; q1.y = v[5]; q1.z = v[6]; q1.w = v[7];
    *(float4*)&p[0] = q0;
    *(float4*)&p[4] = q1;
  }
}

// ---------------------------------------------------------------------------
// K2 (trans-pipe-bound): block (b, 4 s-rows), thread t = tid.
//   mu'[s][t] = -2 * sum_u nu_u * rcp(fma(Ed[s,u], EeT[u,t], 1))
// EeT: coalesced dword (lane=t). Ed/nu: wave-cooperative vload + v_readlane
// (rl overhead ~20% over trans floor; no SMEM latency). Fused row-softmax.
// grid (64, 8) = 512 blocks.
// ---------------------------------------------------------------------------
__global__ __launch_bounds__(256) void coatt_k2_mu(
    const float* __restrict__ nu, float* __restrict__ ws) {
  float* __restrict__ alphas = ws + ALPHA_OFF;
  float* __restrict__ maxmu = ws + MAXMU_OFF;
  const int b = blockIdx.y;
  const int sBase = blockIdx.x * 4;
  const int tid = threadIdx.x;
  const int w = tid >> 6, lane = tid & 63;
  const float* __restrict__ Ee_b = ws + EET_OFF + (size_t)b * U_ * TE_ + tid;
  // cooperative Ed pointer: lane -> (s = lane>>4, uu = lane&15)
  const float* __restrict__ EdCoop =
      ws + ED_OFF + (size_t)(b * TD_ + sBase + (lane >> 4)) * U_ + (lane & 15);

  float acc0 = 0.f, acc1 = 0.f, acc2 = 0.f, acc3 = 0.f;
  for (int c = 0; c < 4; ++c) {
    const float nureg = nu[c * 64 + lane];   // 64 nu values in this wave
#pragma unroll
    for (int q = 0; q < 4; ++q) {
      const int u0 = c * 64 + q * 16;
      const float edreg = EdCoop[u0];        // 4 s x 16 u cooperative
      float ee[16];
#pragma unroll
      for (int j = 0; j < 16; ++j) ee[j] = Ee_b[(u0 + j) * TE_];  // coalesced
#pragma unroll
      for (int j = 0; j < 16; ++j) {
        const float nv = rdlane(nureg, q * 16 + j);
        const float e0 = rdlane(edreg, j);
        const float e1 = rdlane(edreg, 16 + j);
        const float e2 = rdlane(edreg, 32 + j);
        const float e3 = rdlane(edreg, 48 + j);
        acc0 = fmaf(nv, frcp(fmaf(e0, ee[j], 1.0f)), acc0);
        acc1 = fmaf(nv, frcp(fmaf(e1, ee[j], 1.0f)), acc1);
        acc2 = fmaf(nv, frcp(fmaf(e2, ee[j], 1.0f)), acc2);
        acc3 = fmaf(nv, frcp(fmaf(e3, ee[j], 1.0f)), acc3);
      }
    }
  }
  // mu' = -2*acc. Fused softmax over t (256 threads = 4 waves).
  float v[4] = {-2.f * acc0, -2.f * acc1, -2.f * acc2, -2.f * acc3};
  __shared__ float part[4][4];  // [s][wave]
  float m[4];
#pragma unroll
  for (int s = 0; s < 4; ++s) {
    m[s] = v[s];
#pragma unroll
    for (int off = 32; off > 0; off >>= 1) m[s] = fmaxf(m[s], __shfl_xor(m[s], off));
    if (lane == 0) part[s][w] = m[s];
  }
  __syncthreads();
#pragma unroll
  for (int s = 0; s < 4; ++s)
    m[s] = fmaxf(fmaxf(part[s][0], part[s][1]), fmaxf(part[s][2], part[s][3]));
  __syncthreads();
  float e[4], sm[4];
#pragma unroll
  for (int s = 0; s < 4; ++s) {
    e[s] = fexp2((v[s] - m[s]) * LOG2E_F);
    sm[s] = e[s];
#pragma unroll
    for (int off = 32; off > 0; off >>= 1) sm[s] += __shfl_xor(sm[s], off);
    if (lane == 0) part[s][w] = sm[s];
  }
  __syncthreads();
  float* __restrict__ al = alphas + (size_t)(b * TD_ + sBase) * TE_;
#pragma unroll
  for (int s = 0; s < 4; ++s) {
    const float tot = (part[s][0] + part[s][1]) + (part[s][2] + part[s][3]);
    al[s * TE_ + tid] = e[s] * frcp(tot);
  }
  if (tid == 0) {
#pragma unroll
    for (int s = 0; s < 4; ++s) maxmu[b * TD_ + sBase + s] = m[s];
  }
}

// ---------------------------------------------------------------------------
// K3: max_alphas = softmax_s(maxmu[b,:]); h_hat[b,d] = sum_s de[b,s,d]*ma[s].
// grid (8 dChunks, 8 b), 256 threads.
// ---------------------------------------------------------------------------
__global__ __launch_bounds__(256) void coatt_k3_hhat(
    const float* __restrict__ de, float* __restrict__ ws) {
  const float* __restrict__ maxmu = ws + MAXMU_OFF;
  float* __restrict__ hhat = ws + HH_OFF;
  const int b = blockIdx.y;
  const int dBase = blockIdx.x * 32;
  const int tid = threadIdx.x;
  const int w = tid >> 6, lane = tid & 63;
  __shared__ float red[8];
  __shared__ float malpha[256];
  __shared__ float acc_red[256];
  const float v = maxmu[b * TD_ + tid];
  float m = v;
#pragma unroll
  for (int off = 32; off > 0; off >>= 1) m = fmaxf(m, __shfl_xor(m, off));
  if (lane == 0) red[w] = m;
  __syncthreads();
  m = fmaxf(fmaxf(red[0], red[1]), fmaxf(red[2], red[3]));
  const float e = fexp2((v - m) * LOG2E_F);
  float sm = e;
#pragma unroll
  for (int off = 32; off > 0; off >>= 1) sm += __shfl_xor(sm, off);
  if (lane == 0) red[4 + w] = sm;
  __syncthreads();
  sm = (red[4] + red[5]) + (red[6] + red[7]);
  malpha[tid] = e * frcp(sm);
  __syncthreads();
  const int dl = tid & 31, sg = tid >> 5;
  float acc = 0.f;
  for (int s = sg * 32; s < sg * 32 + 32; ++s)
    acc = fmaf(de[(b * TD_ + s) * D_ + dBase + dl], malpha[s], acc);
  acc_red[tid] = acc;
  __syncthreads();
  if (tid < 32) {
    float t = acc_red[tid];
#pragma unroll
    for (int g = 1; g < 8; ++g) t += acc_red[g * 32 + tid];
    hhat[b * D_ + dBase + tid] = t;
  }
}

// ---------------------------------------------------------------------------
// K4: sum_en[s,d] = sum_t alphas[s,t]*en[t,d]; alphas via cooperative vload +
// v_readlane (4 s x 16 t per wave-load), en coalesced (lane=d). Fused concat:
// out = [de | sum_en | de*sum_en | de*h_hat]. grid (64, 8) = 512 blocks.
// ---------------------------------------------------------------------------
__global__ __launch_bounds__(256) void coatt_k4_out(
    const float* __restrict__ en, const float* __restrict__ de,
    const float* __restrict__ ws, float* __restrict__ out) {
  const float* __restrict__ hhat = ws + HH_OFF;
  const int b = blockIdx.y;
  const int sBase = blockIdx.x * 4;
  const int tid = threadIdx.x;
  const int lane = tid & 63;
  const int d = tid;
  // cooperative alphas pointer: lane -> (s = lane>>4, tt = lane&15)
  const float* __restrict__ alCoop =
      ws + ALPHA_OFF + (size_t)(b * TD_ + sBase + (lane >> 4)) * TE_ + (lane & 15);
  const float* __restrict__ en_b = en + (size_t)b * TE_ * D_ + d;

  float acc0 = 0.f, acc1 = 0.f, acc2 = 0.f, acc3 = 0.f;
  for (int t0 = 0; t0 < TE_; t0 += 16) {
    const float alreg = alCoop[t0];          // 4 s x 16 t cooperative
    float env[16];
#pragma unroll
    for (int j = 0; j < 16; ++j) env[j] = en_b[(t0 + j) * D_];  // coalesced
#pragma unroll
    for (int j = 0; j < 16; ++j) {
      acc0 = fmaf(rdlane(alreg, j),      env[j], acc0);
      acc1 = fmaf(rdlane(alreg, 16 + j), env[j], acc1);
      acc2 = fmaf(rdlane(alreg, 32 + j), env[j], acc2);
      acc3 = fmaf(rdlane(alreg, 48 + j), env[j], acc3);
    }
  }
  const float hh = hhat[b * D_ + d];
  const float se[4] = {acc0, acc1, acc2, acc3};
#pragma unroll
  for (int s = 0; s < 4; ++s) {
    const float dd = de[(size_t)(b * TD_ + sBase + s) * D_ + d];
    float* o = out + (size_t)(b * TD_ + sBase + s) * (4 * D_);
    o[d] = dd;
    o[D_ + d] = se[s];
    o[2 * D_ + d] = dd * se[s];
    o[3 * D_ + d] = dd * hh;
  }
}

extern "C" void kernel_launch(void* const* d_in, const int* in_sizes, int n_in,
                              void* d_out, int out_size, void* d_ws, size_t ws_size,
                              hipStream_t stream) {
  (void)in_sizes; (void)n_in; (void)out_size; (void)ws_size;
  const float* en   = (const float*)d_in[0];
  const float* de   = (const float*)d_in[1];
  const float* w_en = (const float*)d_in[2];
  const float* w_de = (const float*)d_in[3];
  const float* nu   = (const float*)d_in[4];
  float* out = (float*)d_out;
  float* ws  = (float*)d_ws;

  coatt_k1_proj<<<dim3(512), 256, 0, stream>>>(en, de, w_en, w_de, ws);
  coatt_k2_mu<<<dim3(64, 8), 256, 0, stream>>>(nu, ws);
  coatt_k3_hhat<<<dim3(8, 8), 256, 0, stream>>>(de, ws);
  coatt_k4_out<<<dim3(64, 8), 256, 0, stream>>>(en, de, ws, out);
}

// Round 7
// 128.868 us; speedup vs baseline: 1.3498x; 1.0766x over previous
//
#include <hip/hip_runtime.h>

// Problem constants
#define B_   8
#define TE_  256
#define TD_  256
#define D_   256
#define U_   256

// Workspace layout (float offsets). ~6 MB.
#define EET_OFF   0        // (B, U, TE)  Ee^T = exp2(2log2e * en@w_en), TRANSPOSED
#define ED_OFF    524288   // (B, TD, U)  Ed = exp2(2log2e * de@w_de)
#define ALPHA_OFF 1048576  // (B, TD, TE) alphas
#define MAXMU_OFF 1572864  // (B, TD)     row max of mu'

__device__ __forceinline__ float fexp2(float x) {
#if __has_builtin(__builtin_amdgcn_exp2f)
  return __builtin_amdgcn_exp2f(x);
#else
  return exp2f(x);
#endif
}
__device__ __forceinline__ float frcp(float x) {
#if __has_builtin(__builtin_amdgcn_rcpf)
  return __builtin_amdgcn_rcpf(x);
#else
  return 1.0f / x;
#endif
}
__device__ __forceinline__ float rdlane(float v, int l) {
  return __int_as_float(__builtin_amdgcn_readlane(__float_as_int(v), l));
}

#define LOG2E_F 1.4426950408889634f
#define TWO_LOG2E_F 2.8853900817779268f

// ---------------------------------------------------------------------------
// K1 (pipelined readlane GEMM): block = 8 rows x 256 u; wave w owns 2 rows,
// lane covers u4 = lane*4 (b128 W loads). Register-double-buffered 8-k W
// chunks + A-window prefetch (branch-free via address wrap). rl:fma = 1:4.
// __launch_bounds__(256,2) so the compiler keeps ~90 VGPRs of loads in
// flight (R6 failed at VGPR_Count=32: every load's L2 latency exposed).
// grid 512 (2 blk/CU): bi<256 en->EeT (LDS-transpose epilogue), else de->Ed.
// ---------------------------------------------------------------------------
__global__ __launch_bounds__(256, 2) void coatt_k1_proj(
    const float* __restrict__ en, const float* __restrict__ de,
    const float* __restrict__ w_en, const float* __restrict__ w_de,
    float* __restrict__ ws) {
  const int bi = blockIdx.x;
  const int which = bi >> 8;                 // 0: en, 1: de
  const float* __restrict__ A = which ? de : en;      // (2048, 256)
  const float* __restrict__ W = which ? w_de : w_en;  // (256, 256)
  const int r0 = (bi & 255) * 8;
  const int tid = threadIdx.x;
  const int w = tid >> 6, lane = tid & 63;
  const int rowW = r0 + w * 2;
  const int u4 = lane * 4;

  // cooperative A pointer: lane -> (row = lane>>5, k = lane&31); one vload
  // per 32-k window holds the wave's 2x32 A-tile.
  const float* __restrict__ Arow = A + (size_t)(rowW + (lane >> 5)) * D_ + (lane & 31);

  float4 acc0 = {0, 0, 0, 0}, acc1 = {0, 0, 0, 0};
  float areg = Arow[0];
  float4 wbuf[8], wnxt[8];
#pragma unroll
  for (int j = 0; j < 8; ++j) wbuf[j] = *(const float4*)&W[j * U_ + u4];

  for (int win = 0; win < 8; ++win) {
    const float aNxt = Arow[((win + 1) & 7) * 32];  // wraps: last load unused
#pragma unroll
    for (int q = 0; q < 4; ++q) {
      const int kb = win * 32 + q * 8;
      const int kn = (kb + 8) & 255;  // wraps to row 0 on last chunk (unused)
#pragma unroll
      for (int j = 0; j < 8; ++j)
        wnxt[j] = *(const float4*)&W[(kn + j) * U_ + u4];  // prefetch, in flight
#pragma unroll
      for (int k = 0; k < 8; ++k) {
        const float a0 = rdlane(areg, q * 8 + k);
        const float a1 = rdlane(areg, 32 + q * 8 + k);
        acc0.x = fmaf(a0, wbuf[k].x, acc0.x);
        acc0.y = fmaf(a0, wbuf[k].y, acc0.y);
        acc0.z = fmaf(a0, wbuf[k].z, acc0.z);
        acc0.w = fmaf(a0, wbuf[k].w, acc0.w);
        acc1.x = fmaf(a1, wbuf[k].x, acc1.x);
        acc1.y = fmaf(a1, wbuf[k].y, acc1.y);
        acc1.z = fmaf(a1, wbuf[k].z, acc1.z);
        acc1.w = fmaf(a1, wbuf[k].w, acc1.w);
      }
#pragma unroll
      for (int j = 0; j < 8; ++j) wbuf[j] = wnxt[j];
    }
    areg = aNxt;
  }

  __shared__ float TT[8][257];  // en-half transpose staging
  if (which) {
    float* __restrict__ out = ws + ED_OFF;
    float4 o0, o1;
    o0.x = fexp2(acc0.x * TWO_LOG2E_F); o0.y = fexp2(acc0.y * TWO_LOG2E_F);
    o0.z = fexp2(acc0.z * TWO_LOG2E_F); o0.w = fexp2(acc0.w * TWO_LOG2E_F);
    o1.x = fexp2(acc1.x * TWO_LOG2E_F); o1.y = fexp2(acc1.y * TWO_LOG2E_F);
    o1.z = fexp2(acc1.z * TWO_LOG2E_F); o1.w = fexp2(acc1.w * TWO_LOG2E_F);
    *(float4*)&out[(rowW + 0) * U_ + u4] = o0;
    *(float4*)&out[(rowW + 1) * U_ + u4] = o1;
  } else {
    const float* a0p = (const float*)&acc0;
    const float* a1p = (const float*)&acc1;
#pragma unroll
    for (int j = 0; j < 4; ++j) {
      TT[w * 2 + 0][u4 + j] = fexp2(a0p[j] * TWO_LOG2E_F);
      TT[w * 2 + 1][u4 + j] = fexp2(a1p[j] * TWO_LOG2E_F);
    }
    __syncthreads();
    const int b = r0 >> 8, t0 = r0 & 255;
    float v[8];
#pragma unroll
    for (int k = 0; k < 8; ++k) v[k] = TT[k][tid];  // conflict-free (stride 257)
    float* __restrict__ p = ws + EET_OFF + (size_t)(b * U_ + tid) * TE_ + t0;
    float4 q0, q1;
    q0.x = v[0]; q0.y = v[1]; q0.z = v[2]; q0.w = v[3];
    q1.x = v[4]; q1.y = v[5]; q1.z = v[6]; q1.w = v[7];
    *(float4*)&p[0] = q0;
    *(float4*)&p[4] = q1;
  }
}

// ---------------------------------------------------------------------------
// K2 (trans-pipe-bound): block (b, 4 s-rows), thread t = tid.
//   mu'[s][t] = -2 * sum_u nu_u * rcp(fma(Ed[s,u], EeT[u,t], 1))
// EeT: coalesced dword, PREFETCHED one 16-u iter ahead. Ed/nu: uniform ->
// s_load (only ~20 dwordx4 per ~400-cyc iter: benign, unlike R5-K1's ratio).
// Fused row-softmax over t. grid (64, 8) = 512 blocks.
// ---------------------------------------------------------------------------
__global__ __launch_bounds__(256, 2) void coatt_k2_mu(
    const float* __restrict__ nu, float* __restrict__ ws) {
  float* __restrict__ alphas = ws + ALPHA_OFF;
  float* __restrict__ maxmu = ws + MAXMU_OFF;
  const int b = blockIdx.y;
  const int sBase = blockIdx.x * 4;
  const int tid = threadIdx.x;
  const int w = tid >> 6, lane = tid & 63;
  const float* __restrict__ Ee_b = ws + EET_OFF + (size_t)b * U_ * TE_ + tid;
  const float* __restrict__ Ed_b = ws + ED_OFF + (size_t)(b * TD_ + sBase) * U_;

  float ee[16], een[16];
#pragma unroll
  for (int j = 0; j < 16; ++j) ee[j] = Ee_b[j * TE_];

  float acc0 = 0.f, acc1 = 0.f, acc2 = 0.f, acc3 = 0.f;
  for (int u0 = 0; u0 < U_; u0 += 16) {
    const int un = (u0 + 16) & 255;  // wraps on last iter (prefetch unused)
#pragma unroll
    for (int j = 0; j < 16; ++j) een[j] = Ee_b[(un + j) * TE_];
#pragma unroll
    for (int q = 0; q < 4; ++q) {
      const float4 nv = *(const float4*)&nu[u0 + q * 4];            // s_load
      const float4 e0 = *(const float4*)&Ed_b[0 * U_ + u0 + q * 4]; // s_load
      const float4 e1 = *(const float4*)&Ed_b[1 * U_ + u0 + q * 4];
      const float4 e2 = *(const float4*)&Ed_b[2 * U_ + u0 + q * 4];
      const float4 e3 = *(const float4*)&Ed_b[3 * U_ + u0 + q * 4];
      const float* nvp = (const float*)&nv;
      const float* p0 = (const float*)&e0;
      const float* p1 = (const float*)&e1;
      const float* p2 = (const float*)&e2;
      const float* p3 = (const float*)&e3;
#pragma unroll
      for (int j = 0; j < 4; ++j) {
        const float eev = ee[q * 4 + j];
        acc0 = fmaf(nvp[j], frcp(fmaf(p0[j], eev, 1.0f)), acc0);
        acc1 = fmaf(nvp[j], frcp(fmaf(p1[j], eev, 1.0f)), acc1);
        acc2 = fmaf(nvp[j], frcp(fmaf(p2[j], eev, 1.0f)), acc2);
        acc3 = fmaf(nvp[j], frcp(fmaf(p3[j], eev, 1.0f)), acc3);
      }
    }
#pragma unroll
    for (int j = 0; j < 16; ++j) ee[j] = een[j];
  }
  // mu' = -2*acc. Fused softmax over t (256 threads = 4 waves).
  float v[4] = {-2.f * acc0, -2.f * acc1, -2.f * acc2, -2.f * acc3};
  __shared__ float part[4][4];  // [s][wave]
  float m[4];
#pragma unroll
  for (int s = 0; s < 4; ++s) {
    m[s] = v[s];
#pragma unroll
    for (int off = 32; off > 0; off >>= 1) m[s] = fmaxf(m[s], __shfl_xor(m[s], off));
    if (lane == 0) part[s][w] = m[s];
  }
  __syncthreads();
#pragma unroll
  for (int s = 0; s < 4; ++s)
    m[s] = fmaxf(fmaxf(part[s][0], part[s][1]), fmaxf(part[s][2], part[s][3]));
  __syncthreads();
  float e[4], sm[4];
#pragma unroll
  for (int s = 0; s < 4; ++s) {
    e[s] = fexp2((v[s] - m[s]) * LOG2E_F);
    sm[s] = e[s];
#pragma unroll
    for (int off = 32; off > 0; off >>= 1) sm[s] += __shfl_xor(sm[s], off);
    if (lane == 0) part[s][w] = sm[s];
  }
  __syncthreads();
  float* __restrict__ al = alphas + (size_t)(b * TD_ + sBase) * TE_;
#pragma unroll
  for (int s = 0; s < 4; ++s) {
    const float tot = (part[s][0] + part[s][1]) + (part[s][2] + part[s][3]);
    al[s * TE_ + tid] = e[s] * frcp(tot);
  }
  if (tid == 0) {
#pragma unroll
    for (int s = 0; s < 4; ++s) maxmu[b * TD_ + sBase + s] = m[s];
  }
}

// ---------------------------------------------------------------------------
// K4 (fused, replaces old K3+K4): per block (b, 4 s-rows), thread d = tid.
//  a) max_alphas = softmax_s(maxmu[b,:]) recomputed per-wave in registers
//     (coop b128 load + shuffle reductions; no LDS, no barrier)
//  b) hh[d] = sum_s de[b,s,d]*malpha[s] (coalesced de, rdlane broadcast)
//  c) sum_en[s,d] = sum_t alphas[s,t]*en[t,d]: alphas s_load, en prefetched
//  d) concat: out = [de | sum_en | de*sum_en | de*hh]
// grid (64, 8) = 512 blocks.
// ---------------------------------------------------------------------------
__global__ __launch_bounds__(256, 2) void coatt_k4_out(
    const float* __restrict__ en, const float* __restrict__ de,
    const float* __restrict__ ws, float* __restrict__ out) {
  const float* __restrict__ maxmu = ws + MAXMU_OFF;
  const int b = blockIdx.y;
  const int sBase = blockIdx.x * 4;
  const int tid = threadIdx.x;
  const int lane = tid & 63;
  const int d = tid;

  // (a) malpha in registers, redundant per wave
  float4 mv = *(const float4*)&maxmu[b * TD_ + lane * 4];
  float mx = fmaxf(fmaxf(mv.x, mv.y), fmaxf(mv.z, mv.w));
#pragma unroll
  for (int off = 32; off > 0; off >>= 1) mx = fmaxf(mx, __shfl_xor(mx, off));
  float4 ex;
  ex.x = fexp2((mv.x - mx) * LOG2E_F);
  ex.y = fexp2((mv.y - mx) * LOG2E_F);
  ex.z = fexp2((mv.z - mx) * LOG2E_F);
  ex.w = fexp2((mv.w - mx) * LOG2E_F);
  float ss = (ex.x + ex.y) + (ex.z + ex.w);
#pragma unroll
  for (int off = 32; off > 0; off >>= 1) ss += __shfl_xor(ss, off);
  const float inv = frcp(ss);
  float mal[4] = {ex.x * inv, ex.y * inv, ex.z * inv, ex.w * inv};

  // (b) hh for this thread's d
  const float* __restrict__ de_b = de + (size_t)b * TD_ * D_ + d;
  float hh = 0.f;
#pragma unroll 8
  for (int s4 = 0; s4 < 64; ++s4) {
#pragma unroll
    for (int c = 0; c < 4; ++c)
      hh = fmaf(de_b[(s4 * 4 + c) * D_], rdlane(mal[c], s4), hh);
  }

  // (c) sum_en: alphas s_load (uniform), en coalesced + prefetch
  const float* __restrict__ al = ws + ALPHA_OFF + (size_t)(b * TD_ + sBase) * TE_;
  const float* __restrict__ en_b = en + (size_t)b * TE_ * D_ + d;
  float env[16], envn[16];
#pragma unroll
  for (int j = 0; j < 16; ++j) env[j] = en_b[j * D_];
  float acc0 = 0.f, acc1 = 0.f, acc2 = 0.f, acc3 = 0.f;
  for (int t0 = 0; t0 < TE_; t0 += 16) {
    const int tn = (t0 + 16) & 255;
#pragma unroll
    for (int j = 0; j < 16; ++j) envn[j] = en_b[(tn + j) * D_];
#pragma unroll
    for (int q = 0; q < 4; ++q) {
      const float4 a0 = *(const float4*)&al[0 * TE_ + t0 + q * 4];  // s_load
      const float4 a1 = *(const float4*)&al[1 * TE_ + t0 + q * 4];
      const float4 a2 = *(const float4*)&al[2 * TE_ + t0 + q * 4];
      const float4 a3 = *(const float4*)&al[3 * TE_ + t0 + q * 4];
      const float* q0 = (const float*)&a0;
      const float* q1 = (const float*)&a1;
      const float* q2 = (const float*)&a2;
      const float* q3 = (const float*)&a3;
#pragma unroll
      for (int j = 0; j < 4; ++j) {
        const float e = env[q * 4 + j];
        acc0 = fmaf(q0[j], e, acc0);
        acc1 = fmaf(q1[j], e, acc1);
        acc2 = fmaf(q2[j], e, acc2);
        acc3 = fmaf(q3[j], e, acc3);
      }
    }
#pragma unroll
    for (int j = 0; j < 16; ++j) env[j] = envn[j];
  }

  // (d) concat epilogue
  const float se[4] = {acc0, acc1, acc2, acc3};
#pragma unroll
  for (int s = 0; s < 4; ++s) {
    const float dd = de[(size_t)(b * TD_ + sBase + s) * D_ + d];
    float* o = out + (size_t)(b * TD_ + sBase + s) * (4 * D_);
    o[d] = dd;
    o[D_ + d] = se[s];
    o[2 * D_ + d] = dd * se[s];
    o[3 * D_ + d] = dd * hh;
  }
}

extern "C" void kernel_launch(void* const* d_in, const int* in_sizes, int n_in,
                              void* d_out, int out_size, void* d_ws, size_t ws_size,
                              hipStream_t stream) {
  (void)in_sizes; (void)n_in; (void)out_size; (void)ws_size;
  const float* en   = (const float*)d_in[0];
  const float* de   = (const float*)d_in[1];
  const float* w_en = (const float*)d_in[2];
  const float* w_de = (const float*)d_in[3];
  const float* nu   = (const float*)d_in[4];
  float* out = (float*)d_out;
  float* ws  = (float*)d_ws;

  coatt_k1_proj<<<dim3(512), 256, 0, stream>>>(en, de, w_en, w_de, ws);
  coatt_k2_mu<<<dim3(64, 8), 256, 0, stream>>>(nu, ws);
  coatt_k4_out<<<dim3(64, 8), 256, 0, stream>>>(en, de, ws, out);
}